// Round 11
// baseline (204.739 us; speedup 1.0000x reference)
//
#include <hip/hip_runtime.h>
#include <cstdint>
#include <cstddef>

static constexpr int NN = 100000;
static constexpr int NE = 1600000;
static constexpr float NEG = 0.2f;
static constexpr int NBUCK = 49;                 // dst >> 11 (2048 nodes/bucket)
static constexpr int BCAP  = 36864;              // mean 32768 + ~22 sigma slack
static constexpr int NBLK1 = 512;
static constexpr int CHUNK1 = (NE + NBLK1 - 1) / NBLK1;  // 3125 (<= 4*1024)

typedef __attribute__((ext_vector_type(8))) short short8v;   // 8 bf16 (4 VGPRs)
typedef __attribute__((ext_vector_type(4))) float floatx4;   // 4 f32 acc

// ---------------------------------------------------------------------------
__device__ inline short8v cvt8(const float4 a, const float4 b)
{
  const float v[8] = {a.x, a.y, a.z, a.w, b.x, b.y, b.z, b.w};
  uint32_t q[8];
#pragma unroll
  for (int j = 0; j < 8; ++j) {
    uint32_t u = __float_as_uint(v[j]);
    u += 0x7fff + ((u >> 16) & 1);   // round-to-nearest-even
    q[j] = u >> 16;
  }
  union { uint32_t u[4]; short8v s; } r;
  r.u[0] = q[0] | (q[1] << 16);
  r.u[1] = q[2] | (q[3] << 16);
  r.u[2] = q[4] | (q[5] << 16);
  r.u[3] = q[6] | (q[7] << 16);
  return r.s;
}

__device__ inline uint32_t cvt1(float x)
{
  uint32_t u = __float_as_uint(x);
  u += 0x7fff + ((u >> 16) & 1);
  return u >> 16;
}

// ---------------------------------------------------------------------------
// MFMA projection GEMM, self-contained: each wave converts its own 64
// B-columns f32->bf16 once (L2-cached weights), A staged through swizzled
// LDS once per block. Wave 3 additionally computes the 4 attn-logit columns.
// Outputs: src_fc bf16 (cols 0-127), dst_fc bf16 incl. bias (cols 128-255),
// attn_s/attn_d f32.
// ---------------------------------------------------------------------------
__global__ __launch_bounds__(256) void gemm_kernel(
    const float* __restrict__ feat, const float* __restrict__ Wsrc,
    const float* __restrict__ Wdst, const float* __restrict__ asrc,
    const float* __restrict__ adst, const float* __restrict__ bdst,
    ushort* __restrict__ src_fc, ushort* __restrict__ dst_fc,
    float* __restrict__ attn_s, float* __restrict__ attn_d)
{
  __shared__ __align__(16) ushort atile[2048];   // 16 x 128 bf16, swizzled

  const int t    = threadIdx.x;
  const int lane = t & 63;
  const int w    = t >> 6;                 // wave 0..3
  const int c0   = w * 64;
  const int colq = lane & 15;
  const int kgrp = lane >> 4;

  // B fragments: convert this wave's 64 columns from f32 weights (one-time).
  short8v bf[4][4];
#pragma unroll
  for (int nt = 0; nt < 4; ++nt) {
    const int col = c0 + nt * 16 + colq;
    const float* wrow = (col < 128) ? (Wsrc + (size_t)col * 128)
                                    : (Wdst + (size_t)(col - 128) * 128);
#pragma unroll
    for (int kt = 0; kt < 4; ++kt) {
      const float* p = wrow + kt * 32 + kgrp * 8;
      bf[nt][kt] = cvt8(*(const float4*)p, *(const float4*)(p + 4));
    }
  }
  short8v bfa[4];
  if (w == 3) {
    if (colq < 4) {
      const float* arow = (colq < 2) ? (asrc + colq * 128)
                                     : (adst + (colq - 2) * 128);
#pragma unroll
      for (int kt = 0; kt < 4; ++kt) {
        const float* p = arow + kt * 32 + kgrp * 8;
        bfa[kt] = cvt8(*(const float4*)p, *(const float4*)(p + 4));
      }
    } else {
#pragma unroll
      for (int kt = 0; kt < 4; ++kt)
        bfa[kt] = short8v{0, 0, 0, 0, 0, 0, 0, 0};
    }
  }

  float bias[4];
#pragma unroll
  for (int nt = 0; nt < 4; ++nt) {
    const int col = c0 + nt * 16 + colq;
    bias[nt] = (col >= 128) ? bdst[col - 128] : 0.0f;
  }
  const bool is_dst = (c0 >= 128);

  const int sr = t >> 4;                   // staging row 0..15
  const int sc = t & 15;                   // staging col-group (8 floats)
  const unsigned sw_off = (unsigned)((sr * 256 + sc * 16) ^ ((sr & 7) << 4));
  unsigned rd_off[4];
#pragma unroll
  for (int kt = 0; kt < 4; ++kt)
    rd_off[kt] = (unsigned)((colq * 256 + kt * 64 + kgrp * 16) ^ ((colq & 7) << 4));

  for (int mt = blockIdx.x; mt < NN / 16; mt += gridDim.x) {
    const int row0 = mt * 16;
    {
      const float* ap = feat + (size_t)(row0 + sr) * 128 + sc * 8;
      float4 a = *(const float4*)ap;
      float4 b = *(const float4*)(ap + 4);
      *(short8v*)((char*)atile + sw_off) = cvt8(a, b);
    }
    __syncthreads();
    short8v af[4];
#pragma unroll
    for (int kt = 0; kt < 4; ++kt)
      af[kt] = *(const short8v*)((const char*)atile + rd_off[kt]);
    __syncthreads();   // reads drained before next iter's writes

    floatx4 acc[4] = {{0,0,0,0},{0,0,0,0},{0,0,0,0},{0,0,0,0}};
#pragma unroll
    for (int kt = 0; kt < 4; ++kt)
#pragma unroll
      for (int nt = 0; nt < 4; ++nt)
        acc[nt] = __builtin_amdgcn_mfma_f32_16x16x32_bf16(af[kt], bf[nt][kt],
                                                          acc[nt], 0, 0, 0);
    // C/D: col = lane&15, row = (lane>>4)*4 + reg
#pragma unroll
    for (int nt = 0; nt < 4; ++nt) {
      const int col = c0 + nt * 16 + colq;
#pragma unroll
      for (int j = 0; j < 4; ++j) {
        const int rr = row0 + kgrp * 4 + j;
        if (!is_dst)
          src_fc[(size_t)rr * 128 + col] = (ushort)cvt1(acc[nt][j]);
        else
          dst_fc[(size_t)rr * 128 + (col - 128)] =
              (ushort)cvt1(acc[nt][j] + bias[nt]);
      }
    }
    if (w == 3) {                          // fused attention columns
      floatx4 acca = {0, 0, 0, 0};
#pragma unroll
      for (int kt = 0; kt < 4; ++kt)
        acca = __builtin_amdgcn_mfma_f32_16x16x32_bf16(af[kt], bfa[kt],
                                                       acca, 0, 0, 0);
      if (colq < 4) {
        float* dstp = (colq < 2) ? attn_s : attn_d;
        const int c2 = colq & 1;
#pragma unroll
        for (int j = 0; j < 4; ++j) {
          const int rr = row0 + kgrp * 4 + j;
          dstp[2 * rr + c2] = acca[j];
        }
      }
    }
  }
}

// ---------------------------------------------------------------------------
// Pass 1: coarse-bucket append. Record (u64):
// [src:17 | dloc:11 | w0bf16:16 | w1bf16:16]. Two-pass per block, with dst
// values cached in registers between passes (statically unrolled, <=4/thread).
// ---------------------------------------------------------------------------
__global__ __launch_bounds__(1024) void bucket_kernel(
    const int* __restrict__ src, const int* __restrict__ dst,
    const float2* __restrict__ attn_s, const float2* __restrict__ attn_d,
    int* __restrict__ bucket_next, unsigned long long* __restrict__ tmp)
{
  __shared__ int lofs[NBUCK];
  const int t = threadIdx.x;
  if (t < NBUCK) lofs[t] = 0;
  __syncthreads();

  const int e0 = blockIdx.x * CHUNK1;
  const int e1 = min(e0 + CHUNK1, NE);

  int dreg[4];
#pragma unroll
  for (int k = 0; k < 4; ++k) {
    const int e = e0 + k * 1024 + t;
    dreg[k] = (e < e1) ? dst[e] : -1;
    if (e < e1) atomicAdd(&lofs[dreg[k] >> 11], 1);
  }
  __syncthreads();

  if (t < NBUCK) {
    const int c = lofs[t];
    const int base = atomicAdd(&bucket_next[t], c);
    lofs[t] = t * BCAP + base;
  }
  __syncthreads();

#pragma unroll
  for (int k = 0; k < 4; ++k) {
    const int e = e0 + k * 1024 + t;
    if (e < e1) {
      const int d = dreg[k];
      const int s = src[e];
      const float2 as = attn_s[s];
      const float2 ad = attn_d[d];
      float l0 = as.x + ad.x;
      float l1 = as.y + ad.y;
      l0 = (l0 > 0.0f) ? l0 : NEG * l0;
      l1 = (l1 > 0.0f) ? l1 : NEG * l1;
      const uint32_t wp = cvt1(__expf(l0)) | (cvt1(__expf(l1)) << 16);
      const int pos = atomicAdd(&lofs[d >> 11], 1);
      tmp[pos] = ((unsigned long long)(unsigned)s << 43)
               | ((unsigned long long)(unsigned)(d & 2047) << 32)
               | (unsigned long long)wp;
    }
  }
}

// ---------------------------------------------------------------------------
// Fused rs-build + CSR scatter: one block per bucket (unchanged from R10).
// ---------------------------------------------------------------------------
__global__ __launch_bounds__(1024) void rs_csr_kernel(
    const unsigned long long* __restrict__ tmp,
    const int* __restrict__ bucket_next,
    int* __restrict__ rs, uint2* __restrict__ edges)
{
  __shared__ int hist[2048];
  __shared__ int ps[1024];
  __shared__ int bstart_s;
  const int b = blockIdx.x;
  const int t = threadIdx.x;
  hist[t] = 0;
  hist[t + 1024] = 0;
  if (t == 0) {
    int ssum = 0;
    for (int k = 0; k < b; ++k) ssum += bucket_next[k];
    bstart_s = ssum;
  }
  __syncthreads();

  const int ncnt = bucket_next[b];
  const unsigned long long* base = tmp + (size_t)b * BCAP;
  for (int i = t; i < ncnt; i += 1024)
    atomicAdd(&hist[(int)((base[i] >> 32) & 2047)], 1);
  __syncthreads();

  const int h0 = hist[2 * t];
  const int h1 = hist[2 * t + 1];
  const int pv = h0 + h1;
  ps[t] = pv;
  __syncthreads();
  int x = pv;
  for (int o = 1; o < 1024; o <<= 1) {
    const int y = (t >= o) ? ps[t - o] : 0;
    __syncthreads();
    x += y;
    ps[t] = x;
    __syncthreads();
  }
  const int e0 = bstart_s + x - pv;          // exclusive prefix at node 2t
  hist[2 * t]     = e0;                      // becomes running write cursor
  hist[2 * t + 1] = e0 + h0;
  const int n0 = b * 2048 + 2 * t;
  if (n0 < NN)     rs[n0] = e0;
  if (n0 + 1 < NN) rs[n0 + 1] = e0 + h0;
  if (b == NBUCK - 1 && t == 0) rs[NN] = NE;
  __syncthreads();

  for (int i = t; i < ncnt; i += 1024) {
    const unsigned long long r = base[i];
    const int s = (int)(r >> 43);
    const int dloc = (int)((r >> 32) & 2047);
    const int pos = atomicAdd(&hist[dloc], 1);
    edges[pos] = make_uint2((unsigned)s * 256u, (uint32_t)r);
  }
}

// ---------------------------------------------------------------------------
// Aggregation: one wave per destination node; 8 B records (bf16 weights);
// 3-stage, 8-edge-wide pipeline. Writes out = agg/denom + dst_fc for EVERY
// node (no read-modify-write of out; dst_fc row read is coalesced/streaming).
// ---------------------------------------------------------------------------
__global__ __launch_bounds__(256) void aggregate_kernel(
    const int* __restrict__ rs, const uint2* __restrict__ edges,
    const ushort* __restrict__ src_fc, const ushort* __restrict__ dst_fc,
    float* __restrict__ out)
{
  int wid = (int)((blockIdx.x * (size_t)blockDim.x + threadIdx.x) >> 6);
  if (wid >= NN) return;
  wid = __builtin_amdgcn_readfirstlane(wid);
  const int lane = threadIdx.x & 63;
  const unsigned lane4 = lane * 4;          // byte offset within bf16 row
  const int start = rs[wid];
  const int end = rs[wid + 1];
  const int deg = end - start;

  // own dst row (residual branch), issued early
  const uint32_t dv =
      *(const uint32_t*)((const char*)dst_fc + ((unsigned)wid * 256u + lane4));
  const float dx = __uint_as_float(dv << 16);
  const float dy = __uint_as_float(dv & 0xffff0000u);
  float2* po = (float2*)(out + (size_t)wid * 128 + 2 * lane);

  if (deg == 0) { *po = make_float2(dx, dy); return; }

  const bool h0 = (lane < 32);
  const char* fcb = (const char*)src_fc;
  const int nb = (deg + 7) >> 3;

  struct Batch { uint2 e[8]; };
  struct Rows  { uint32_t r[8]; };

  auto loadE = [&](int b, Batch& B) {
    const int base = start + b * 8;
#pragma unroll
    for (int j = 0; j < 8; ++j) {
      const int idx = (base + j < end) ? base + j : start;
      B.e[j] = edges[idx];                   // uniform -> scalar loads
    }
  };
  auto loadR = [&](const Batch& B, Rows& R) {
#pragma unroll
    for (int j = 0; j < 8; ++j)
      R.r[j] = *(const uint32_t*)(fcb + (B.e[j].x + lane4));
  };

  float acc0 = 0.0f, acc1 = 0.0f, dh = 0.0f;
  auto compute = [&](int b, const Batch& B, const Rows& R) {
    const int rem = deg - b * 8;
#pragma unroll
    for (int j = 0; j < 8; ++j) {
      const uint32_t wp = (j < rem) ? B.e[j].y : 0u;   // scalar select
      const float w0 = __uint_as_float(wp << 16);
      const float w1 = __uint_as_float(wp & 0xffff0000u);
      const float wh = h0 ? w0 : w1;
      dh += wh;
      acc0 = fmaf(__uint_as_float(R.r[j] << 16), wh, acc0);
      acc1 = fmaf(__uint_as_float(R.r[j] & 0xffff0000u), wh, acc1);
    }
  };

  Batch bA, bB;
  Rows rA;
  loadE(0, bA);
  loadR(bA, rA);
  if (nb > 1) loadE(1, bB); else bB = bA;

  for (int b = 0; b < nb; ++b) {
    Rows rB = rA;
    if (b + 1 < nb) loadR(bB, rB);
    Batch bC = bB;
    if (b + 2 < nb) loadE(b + 2, bC);
    compute(b, bA, rA);
    bA = bB; rA = rB; bB = bC;
  }

  const float inv = 1.0f / dh;
  float2 o;
  o.x = fmaf(acc0, inv, dx);
  o.y = fmaf(acc1, inv, dy);
  *po = o;
}

// ---------------------------------------------------------------------------
extern "C" void kernel_launch(void* const* d_in, const int* in_sizes, int n_in,
                              void* d_out, int out_size, void* d_ws, size_t ws_size,
                              hipStream_t stream)
{
  const float* feat    = (const float*)d_in[0];
  const int*   src_idx = (const int*)d_in[1];
  const int*   dst_idx = (const int*)d_in[2];
  const float* Wsrc    = (const float*)d_in[3];
  const float* Wdst    = (const float*)d_in[4];
  const float* bdst    = (const float*)d_in[5];
  const float* asrc    = (const float*)d_in[6];
  const float* adst    = (const float*)d_in[7];
  float* out = (float*)d_out;

  char* ws = (char*)d_ws;
  size_t off = 0;
  auto alloc = [&](size_t bytes) -> void* {
    void* p = ws + off;
    off = (off + bytes + 255) & ~(size_t)255;
    return p;
  };
  ushort* src_fc  = (ushort*)alloc((size_t)NN * 128 * sizeof(ushort));   // 25.6 MB
  ushort* dst_fc  = (ushort*)alloc((size_t)NN * 128 * sizeof(ushort));   // 25.6 MB
  float*  attn_s  = (float*)alloc((size_t)NN * 2 * sizeof(float));
  float*  attn_d  = (float*)alloc((size_t)NN * 2 * sizeof(float));
  int*    rs      = (int*)alloc((size_t)(NN + 1) * sizeof(int));
  uint2*  edges   = (uint2*)alloc((size_t)NE * sizeof(uint2));           // 12.8 MB
  unsigned long long* tmp =
      (unsigned long long*)alloc((size_t)NBUCK * BCAP * sizeof(unsigned long long)); // 14.5 MB
  int*    bnext   = (int*)alloc((size_t)NBUCK * sizeof(int));

  hipMemsetAsync(bnext, 0, (size_t)NBUCK * sizeof(int), stream);

  gemm_kernel<<<1563, 256, 0, stream>>>(feat, Wsrc, Wdst, asrc, adst, bdst,
                                        src_fc, dst_fc, attn_s, attn_d);
  bucket_kernel<<<NBLK1, 1024, 0, stream>>>(
      src_idx, dst_idx, (const float2*)attn_s, (const float2*)attn_d,
      bnext, tmp);
  rs_csr_kernel<<<NBUCK, 1024, 0, stream>>>(tmp, bnext, rs, edges);
  aggregate_kernel<<<(NN * 64) / 256, 256, 0, stream>>>(rs, edges, src_fc,
                                                        dst_fc, out);
}

// Round 12
// 194.968 us; speedup vs baseline: 1.0501x; 1.0501x over previous
//
#include <hip/hip_runtime.h>
#include <cstdint>
#include <cstddef>

static constexpr int NN = 100000;
static constexpr int NE = 1600000;
static constexpr float NEG = 0.2f;
static constexpr int NBUCK = 782;                // dst >> 7 (128 nodes/bucket)
static constexpr int BCAP  = 2560;               // mean 2046 + ~11 sigma
static constexpr int NBLK1 = 512;
static constexpr int CHUNK1 = (NE + NBLK1 - 1) / NBLK1;  // 3125 (<= 4*1024)

typedef __attribute__((ext_vector_type(8))) short short8v;   // 8 bf16 (4 VGPRs)
typedef __attribute__((ext_vector_type(4))) float floatx4;   // 4 f32 acc

// ---------------------------------------------------------------------------
__device__ inline short8v cvt8(const float4 a, const float4 b)
{
  const float v[8] = {a.x, a.y, a.z, a.w, b.x, b.y, b.z, b.w};
  uint32_t q[8];
#pragma unroll
  for (int j = 0; j < 8; ++j) {
    uint32_t u = __float_as_uint(v[j]);
    u += 0x7fff + ((u >> 16) & 1);   // round-to-nearest-even
    q[j] = u >> 16;
  }
  union { uint32_t u[4]; short8v s; } r;
  r.u[0] = q[0] | (q[1] << 16);
  r.u[1] = q[2] | (q[3] << 16);
  r.u[2] = q[4] | (q[5] << 16);
  r.u[3] = q[6] | (q[7] << 16);
  return r.s;
}

__device__ inline uint32_t cvt1(float x)
{
  uint32_t u = __float_as_uint(x);
  u += 0x7fff + ((u >> 16) & 1);
  return u >> 16;
}

// ---------------------------------------------------------------------------
// Build wb[272][128] bf16: rows 0-127 Wsrc, 128-255 Wdst, 256-257 a_src,
// 258-259 a_dst, 260-271 zero pad (attn = 4 extra GEMM columns).
// ---------------------------------------------------------------------------
__global__ __launch_bounds__(256) void cvt_w_kernel(
    const float* __restrict__ Wsrc, const float* __restrict__ Wdst,
    const float* __restrict__ asrc, const float* __restrict__ adst,
    ushort* __restrict__ wb)
{
  const int i = (blockIdx.x * 256 + threadIdx.x) * 8;
  if (i >= 34816) return;
  const float* src;
  if (i < 16384)      src = Wsrc + i;
  else if (i < 32768) src = Wdst + (i - 16384);
  else if (i < 33024) src = asrc + (i - 32768);
  else if (i < 33280) src = adst + (i - 33024);
  else { *(short8v*)(wb + i) = short8v{0,0,0,0,0,0,0,0}; return; }
  float4 a = *(const float4*)(src);
  float4 b = *(const float4*)(src + 4);
  *(short8v*)(wb + i) = cvt8(a, b);
}

// ---------------------------------------------------------------------------
// MFMA projection GEMM (R10-proven structure): A staged once per block
// through swizzled LDS; B from pre-converted bf16 wb; wave 3 computes the
// 4 fused attn-logit columns. Outputs src_fc bf16, dst_fc bf16 (+bias),
// attn_s/attn_d f32.
// ---------------------------------------------------------------------------
__global__ __launch_bounds__(256) void gemm_kernel(
    const float* __restrict__ feat, const ushort* __restrict__ wb,
    const float* __restrict__ bdst,
    ushort* __restrict__ src_fc, ushort* __restrict__ dst_fc,
    float* __restrict__ attn_s, float* __restrict__ attn_d)
{
  __shared__ __align__(16) ushort atile[2048];   // 16 x 128 bf16, swizzled

  const int t    = threadIdx.x;
  const int lane = t & 63;
  const int w    = t >> 6;                 // wave 0..3
  const int c0   = w * 64;
  const int colq = lane & 15;
  const int kgrp = lane >> 4;

  short8v bf[4][4];
#pragma unroll
  for (int nt = 0; nt < 4; ++nt)
#pragma unroll
    for (int kt = 0; kt < 4; ++kt)
      bf[nt][kt] = *(const short8v*)(wb + (size_t)(c0 + nt * 16 + colq) * 128
                                        + kt * 32 + kgrp * 8);
  short8v bfa[4];
  if (w == 3) {
#pragma unroll
    for (int kt = 0; kt < 4; ++kt)
      bfa[kt] = *(const short8v*)(wb + (size_t)(256 + colq) * 128
                                     + kt * 32 + kgrp * 8);
  }

  float bias[4];
#pragma unroll
  for (int nt = 0; nt < 4; ++nt) {
    const int col = c0 + nt * 16 + colq;
    bias[nt] = (col >= 128) ? bdst[col - 128] : 0.0f;
  }
  const bool is_dst = (c0 >= 128);

  const int sr = t >> 4;                   // staging row 0..15
  const int sc = t & 15;                   // staging col-group (8 floats)
  const unsigned sw_off = (unsigned)((sr * 256 + sc * 16) ^ ((sr & 7) << 4));
  unsigned rd_off[4];
#pragma unroll
  for (int kt = 0; kt < 4; ++kt)
    rd_off[kt] = (unsigned)((colq * 256 + kt * 64 + kgrp * 16) ^ ((colq & 7) << 4));

  for (int mt = blockIdx.x; mt < NN / 16; mt += gridDim.x) {
    const int row0 = mt * 16;
    {
      const float* ap = feat + (size_t)(row0 + sr) * 128 + sc * 8;
      float4 a = *(const float4*)ap;
      float4 b = *(const float4*)(ap + 4);
      *(short8v*)((char*)atile + sw_off) = cvt8(a, b);
    }
    __syncthreads();
    short8v af[4];
#pragma unroll
    for (int kt = 0; kt < 4; ++kt)
      af[kt] = *(const short8v*)((const char*)atile + rd_off[kt]);
    __syncthreads();   // reads drained before next iter's writes

    floatx4 acc[4] = {{0,0,0,0},{0,0,0,0},{0,0,0,0},{0,0,0,0}};
#pragma unroll
    for (int kt = 0; kt < 4; ++kt)
#pragma unroll
      for (int nt = 0; nt < 4; ++nt)
        acc[nt] = __builtin_amdgcn_mfma_f32_16x16x32_bf16(af[kt], bf[nt][kt],
                                                          acc[nt], 0, 0, 0);
    // C/D: col = lane&15, row = (lane>>4)*4 + reg
#pragma unroll
    for (int nt = 0; nt < 4; ++nt) {
      const int col = c0 + nt * 16 + colq;
#pragma unroll
      for (int j = 0; j < 4; ++j) {
        const int rr = row0 + kgrp * 4 + j;
        if (!is_dst)
          src_fc[(size_t)rr * 128 + col] = (ushort)cvt1(acc[nt][j]);
        else
          dst_fc[(size_t)rr * 128 + (col - 128)] =
              (ushort)cvt1(acc[nt][j] + bias[nt]);
      }
    }
    if (w == 3) {                          // fused attention columns
      floatx4 acca = {0, 0, 0, 0};
#pragma unroll
      for (int kt = 0; kt < 4; ++kt)
        acca = __builtin_amdgcn_mfma_f32_16x16x32_bf16(af[kt], bfa[kt],
                                                       acca, 0, 0, 0);
      if (colq < 4) {
        float* dstp = (colq < 2) ? attn_s : attn_d;
        const int c2 = colq & 1;
#pragma unroll
        for (int j = 0; j < 4; ++j) {
          const int rr = row0 + kgrp * 4 + j;
          dstp[2 * rr + c2] = acca[j];
        }
      }
    }
  }
}

// ---------------------------------------------------------------------------
// Bucket append (dst>>7, 782 buckets of 128 nodes). Record (u64):
// [src:17 | dloc:7 | w0bf16 | w1bf16]. Two-pass: LDS bucket count -> one
// global reservation per bucket -> dense streaming append.
// ---------------------------------------------------------------------------
__global__ __launch_bounds__(1024) void bucket_kernel(
    const int* __restrict__ src, const int* __restrict__ dst,
    const float2* __restrict__ attn_s, const float2* __restrict__ attn_d,
    int* __restrict__ bucket_next, unsigned long long* __restrict__ tmp)
{
  __shared__ int lofs[NBUCK];
  const int t = threadIdx.x;
  if (t < NBUCK) lofs[t] = 0;
  __syncthreads();

  const int e0 = blockIdx.x * CHUNK1;
  const int e1 = min(e0 + CHUNK1, NE);

  int dreg[4];
#pragma unroll
  for (int k = 0; k < 4; ++k) {
    const int e = e0 + k * 1024 + t;
    dreg[k] = (e < e1) ? dst[e] : -1;
    if (e < e1) atomicAdd(&lofs[dreg[k] >> 7], 1);
  }
  __syncthreads();

  if (t < NBUCK) {
    const int c = lofs[t];
    const int base = atomicAdd(&bucket_next[t], c);
    lofs[t] = t * BCAP + base;
  }
  __syncthreads();

#pragma unroll
  for (int k = 0; k < 4; ++k) {
    const int e = e0 + k * 1024 + t;
    if (e < e1) {
      const int d = dreg[k];
      const int s = src[e];
      const float2 as = attn_s[s];
      const float2 ad = attn_d[d];
      float l0 = as.x + ad.x;
      float l1 = as.y + ad.y;
      l0 = (l0 > 0.0f) ? l0 : NEG * l0;
      l1 = (l1 > 0.0f) ? l1 : NEG * l1;
      const uint32_t wp = cvt1(__expf(l0)) | (cvt1(__expf(l1)) << 16);
      const int bkt = d >> 7;
      const int pos = atomicAdd(&lofs[bkt], 1);
      if (pos < (bkt + 1) * BCAP)          // overflow guard (P ~ 1e-20)
        tmp[pos] = ((unsigned long long)(unsigned)s << 43)
                 | ((unsigned long long)(unsigned)(d & 127) << 32)
                 | (unsigned long long)wp;
    }
  }
}

// ---------------------------------------------------------------------------
// Fused CSR-build + aggregation: one block (512 thr, 8 waves) per 128-node
// bucket. Bucket's records -> LDS histogram -> scan -> LDS scatter; then
// each wave aggregates 16 nodes straight from LDS records (no global edges
// array, no rs array). out = agg/denom + dst_fc for every node.
// ---------------------------------------------------------------------------
__global__ __launch_bounds__(512) void agg_kernel(
    const unsigned long long* __restrict__ tmp,
    const int* __restrict__ bucket_next,
    const ushort* __restrict__ src_fc, const ushort* __restrict__ dst_fc,
    float* __restrict__ out)
{
  __shared__ unsigned long long lrec[BCAP];   // 20.5 KB
  __shared__ int lcnt[128];
  __shared__ int ps[128];
  __shared__ int lstart[129];
  __shared__ int lcur[128];

  const int b = blockIdx.x;
  const int t = threadIdx.x;
  const int ncnt = min(bucket_next[b], BCAP);
  const unsigned long long* base = tmp + (size_t)b * BCAP;

  if (t < 128) lcnt[t] = 0;
  __syncthreads();

  for (int i = t; i < ncnt; i += 512)
    atomicAdd(&lcnt[(int)((base[i] >> 32) & 127)], 1);
  __syncthreads();

  if (t < 128) ps[t] = lcnt[t];
  __syncthreads();
  for (int o = 1; o < 128; o <<= 1) {
    int y = 0;
    if (t < 128 && t >= o) y = ps[t - o];
    __syncthreads();
    if (t < 128) ps[t] += y;
    __syncthreads();
  }
  if (t < 128) {
    lstart[t + 1] = ps[t];
    lcur[t] = ps[t] - lcnt[t];
  }
  if (t == 0) lstart[0] = 0;
  __syncthreads();

  for (int i = t; i < ncnt; i += 512) {
    const unsigned long long r = base[i];
    const int pos = atomicAdd(&lcur[(int)((r >> 32) & 127)], 1);
    lrec[pos] = r;
  }
  __syncthreads();

  // ---- aggregation: wave w handles local nodes w, w+8, ..., w+120 ----
  const int lane = t & 63;
  const int w = t >> 6;
  const bool h0 = (lane < 32);
  const unsigned lane4 = lane * 4;
  const char* fcb = (const char*)src_fc;

  for (int ln = w; ln < 128; ln += 8) {
    const int node = b * 128 + ln;
    if (node >= NN) break;
    const int s0 = lstart[ln];
    const int deg = lstart[ln + 1] - s0;

    const uint32_t dv = *(const uint32_t*)((const char*)dst_fc
                           + ((unsigned)node * 256u + lane4));
    const float dx = __uint_as_float(dv << 16);
    const float dy = __uint_as_float(dv & 0xffff0000u);
    float2* po = (float2*)(out + (size_t)node * 128 + 2 * lane);

    if (deg == 0) { *po = make_float2(dx, dy); continue; }

    const int nb8 = (deg + 7) >> 3;
    unsigned long long rA[8], rB[8];
    uint32_t rowA[8];

    auto loadRec = [&](int bb, unsigned long long* R) {
#pragma unroll
      for (int j = 0; j < 8; ++j) {
        int idx = s0 + bb * 8 + j;
        if (idx >= s0 + deg) idx = s0;
        R[j] = lrec[idx];                    // LDS broadcast, cheap
      }
    };
    auto loadRows = [&](const unsigned long long* R, uint32_t* Rw) {
#pragma unroll
      for (int j = 0; j < 8; ++j)
        Rw[j] = *(const uint32_t*)(fcb
                   + ((unsigned)(R[j] >> 43) * 256u + lane4));
    };

    loadRec(0, rA);
    loadRows(rA, rowA);
    if (nb8 > 1) loadRec(1, rB);

    float acc0 = 0.0f, acc1 = 0.0f, dh = 0.0f;
    for (int bb = 0; bb < nb8; ++bb) {
      uint32_t rowB[8];
      if (bb + 1 < nb8) loadRows(rB, rowB);
      const int rem = deg - bb * 8;
#pragma unroll
      for (int j = 0; j < 8; ++j) {
        const uint32_t wp = (j < rem) ? (uint32_t)rA[j] : 0u;
        const float w0 = __uint_as_float(wp << 16);
        const float w1 = __uint_as_float(wp & 0xffff0000u);
        const float wh = h0 ? w0 : w1;
        dh += wh;
        acc0 = fmaf(__uint_as_float(rowA[j] << 16), wh, acc0);
        acc1 = fmaf(__uint_as_float(rowA[j] & 0xffff0000u), wh, acc1);
      }
      if (bb + 1 < nb8) {
#pragma unroll
        for (int j = 0; j < 8; ++j) { rA[j] = rB[j]; rowA[j] = rowB[j]; }
        if (bb + 2 < nb8) loadRec(bb + 2, rB);
      }
    }

    const float inv = 1.0f / dh;
    float2 o;
    o.x = fmaf(acc0, inv, dx);
    o.y = fmaf(acc1, inv, dy);
    *po = o;
  }
}

// ---------------------------------------------------------------------------
extern "C" void kernel_launch(void* const* d_in, const int* in_sizes, int n_in,
                              void* d_out, int out_size, void* d_ws, size_t ws_size,
                              hipStream_t stream)
{
  const float* feat    = (const float*)d_in[0];
  const int*   src_idx = (const int*)d_in[1];
  const int*   dst_idx = (const int*)d_in[2];
  const float* Wsrc    = (const float*)d_in[3];
  const float* Wdst    = (const float*)d_in[4];
  const float* bdst    = (const float*)d_in[5];
  const float* asrc    = (const float*)d_in[6];
  const float* adst    = (const float*)d_in[7];
  float* out = (float*)d_out;

  char* ws = (char*)d_ws;
  size_t off = 0;
  auto alloc = [&](size_t bytes) -> void* {
    void* p = ws + off;
    off = (off + bytes + 255) & ~(size_t)255;
    return p;
  };
  ushort* src_fc  = (ushort*)alloc((size_t)NN * 128 * sizeof(ushort));   // 25.6 MB
  ushort* dst_fc  = (ushort*)alloc((size_t)NN * 128 * sizeof(ushort));   // 25.6 MB
  float*  attn_s  = (float*)alloc((size_t)NN * 2 * sizeof(float));
  float*  attn_d  = (float*)alloc((size_t)NN * 2 * sizeof(float));
  unsigned long long* tmp =
      (unsigned long long*)alloc((size_t)NBUCK * BCAP * sizeof(unsigned long long)); // 16 MB
  int*    bnext   = (int*)alloc((size_t)NBUCK * sizeof(int));
  ushort* wb      = (ushort*)alloc((size_t)272 * 128 * sizeof(ushort));

  hipMemsetAsync(bnext, 0, (size_t)NBUCK * sizeof(int), stream);

  cvt_w_kernel<<<17, 256, 0, stream>>>(Wsrc, Wdst, asrc, adst, wb);
  gemm_kernel<<<1563, 256, 0, stream>>>(feat, wb, bdst, src_fc, dst_fc,
                                        attn_s, attn_d);
  bucket_kernel<<<NBLK1, 1024, 0, stream>>>(
      src_idx, dst_idx, (const float2*)attn_s, (const float2*)attn_d,
      bnext, tmp);
  agg_kernel<<<NBUCK, 512, 0, stream>>>(tmp, bnext, src_fc, dst_fc, out);
}

// Round 13
// 182.875 us; speedup vs baseline: 1.1196x; 1.0661x over previous
//
#include <hip/hip_runtime.h>
#include <cstdint>
#include <cstddef>

static constexpr int NN = 100000;
static constexpr int NE = 1600000;
static constexpr float NEG = 0.2f;
static constexpr int NBUCK = 49;                 // dst >> 11 (2048 nodes/bucket)
static constexpr int BCAP  = 36864;              // mean 32768 + ~22 sigma slack
static constexpr int NBLK1 = 512;
static constexpr int CHUNK1 = (NE + NBLK1 - 1) / NBLK1;  // 3125 (<= 4*1024)

typedef __attribute__((ext_vector_type(8))) short short8v;   // 8 bf16 (4 VGPRs)
typedef __attribute__((ext_vector_type(4))) float floatx4;   // 4 f32 acc

// ---------------------------------------------------------------------------
__device__ inline short8v cvt8(const float4 a, const float4 b)
{
  const float v[8] = {a.x, a.y, a.z, a.w, b.x, b.y, b.z, b.w};
  uint32_t q[8];
#pragma unroll
  for (int j = 0; j < 8; ++j) {
    uint32_t u = __float_as_uint(v[j]);
    u += 0x7fff + ((u >> 16) & 1);   // round-to-nearest-even
    q[j] = u >> 16;
  }
  union { uint32_t u[4]; short8v s; } r;
  r.u[0] = q[0] | (q[1] << 16);
  r.u[1] = q[2] | (q[3] << 16);
  r.u[2] = q[4] | (q[5] << 16);
  r.u[3] = q[6] | (q[7] << 16);
  return r.s;
}

__device__ inline uint32_t cvt1(float x)
{
  uint32_t u = __float_as_uint(x);
  u += 0x7fff + ((u >> 16) & 1);
  return u >> 16;
}

// ---------------------------------------------------------------------------
// Build wb[272][128] bf16: rows 0-127 Wsrc, 128-255 Wdst, 256-257 a_src,
// 258-259 a_dst, 260-271 zero pad (attn = 4 extra GEMM columns).
// ---------------------------------------------------------------------------
__global__ __launch_bounds__(256) void cvt_w_kernel(
    const float* __restrict__ Wsrc, const float* __restrict__ Wdst,
    const float* __restrict__ asrc, const float* __restrict__ adst,
    ushort* __restrict__ wb)
{
  const int i = (blockIdx.x * 256 + threadIdx.x) * 8;
  if (i >= 34816) return;
  const float* src;
  if (i < 16384)      src = Wsrc + i;
  else if (i < 32768) src = Wdst + (i - 16384);
  else if (i < 33024) src = asrc + (i - 32768);
  else if (i < 33280) src = adst + (i - 33024);
  else { *(short8v*)(wb + i) = short8v{0,0,0,0,0,0,0,0}; return; }
  float4 a = *(const float4*)(src);
  float4 b = *(const float4*)(src + 4);
  *(short8v*)(wb + i) = cvt8(a, b);
}

// ---------------------------------------------------------------------------
// MFMA projection GEMM (R10-proven): A staged once per block through
// swizzled LDS; B from pre-converted bf16 wb; wave 3 computes the 4 fused
// attn-logit columns. Outputs src_fc bf16, dst_fc bf16 (+bias), attn f32.
// ---------------------------------------------------------------------------
__global__ __launch_bounds__(256) void gemm_kernel(
    const float* __restrict__ feat, const ushort* __restrict__ wb,
    const float* __restrict__ bdst,
    ushort* __restrict__ src_fc, ushort* __restrict__ dst_fc,
    float* __restrict__ attn_s, float* __restrict__ attn_d)
{
  __shared__ __align__(16) ushort atile[2048];   // 16 x 128 bf16, swizzled

  const int t    = threadIdx.x;
  const int lane = t & 63;
  const int w    = t >> 6;                 // wave 0..3
  const int c0   = w * 64;
  const int colq = lane & 15;
  const int kgrp = lane >> 4;

  short8v bf[4][4];
#pragma unroll
  for (int nt = 0; nt < 4; ++nt)
#pragma unroll
    for (int kt = 0; kt < 4; ++kt)
      bf[nt][kt] = *(const short8v*)(wb + (size_t)(c0 + nt * 16 + colq) * 128
                                        + kt * 32 + kgrp * 8);
  short8v bfa[4];
  if (w == 3) {
#pragma unroll
    for (int kt = 0; kt < 4; ++kt)
      bfa[kt] = *(const short8v*)(wb + (size_t)(256 + colq) * 128
                                     + kt * 32 + kgrp * 8);
  }

  float bias[4];
#pragma unroll
  for (int nt = 0; nt < 4; ++nt) {
    const int col = c0 + nt * 16 + colq;
    bias[nt] = (col >= 128) ? bdst[col - 128] : 0.0f;
  }
  const bool is_dst = (c0 >= 128);

  const int sr = t >> 4;                   // staging row 0..15
  const int sc = t & 15;                   // staging col-group (8 floats)
  const unsigned sw_off = (unsigned)((sr * 256 + sc * 16) ^ ((sr & 7) << 4));
  unsigned rd_off[4];
#pragma unroll
  for (int kt = 0; kt < 4; ++kt)
    rd_off[kt] = (unsigned)((colq * 256 + kt * 64 + kgrp * 16) ^ ((colq & 7) << 4));

  for (int mt = blockIdx.x; mt < NN / 16; mt += gridDim.x) {
    const int row0 = mt * 16;
    {
      const float* ap = feat + (size_t)(row0 + sr) * 128 + sc * 8;
      float4 a = *(const float4*)ap;
      float4 b = *(const float4*)(ap + 4);
      *(short8v*)((char*)atile + sw_off) = cvt8(a, b);
    }
    __syncthreads();
    short8v af[4];
#pragma unroll
    for (int kt = 0; kt < 4; ++kt)
      af[kt] = *(const short8v*)((const char*)atile + rd_off[kt]);
    __syncthreads();   // reads drained before next iter's writes

    floatx4 acc[4] = {{0,0,0,0},{0,0,0,0},{0,0,0,0},{0,0,0,0}};
#pragma unroll
    for (int kt = 0; kt < 4; ++kt)
#pragma unroll
      for (int nt = 0; nt < 4; ++nt)
        acc[nt] = __builtin_amdgcn_mfma_f32_16x16x32_bf16(af[kt], bf[nt][kt],
                                                          acc[nt], 0, 0, 0);
    // C/D: col = lane&15, row = (lane>>4)*4 + reg
#pragma unroll
    for (int nt = 0; nt < 4; ++nt) {
      const int col = c0 + nt * 16 + colq;
#pragma unroll
      for (int j = 0; j < 4; ++j) {
        const int rr = row0 + kgrp * 4 + j;
        if (!is_dst)
          src_fc[(size_t)rr * 128 + col] = (ushort)cvt1(acc[nt][j]);
        else
          dst_fc[(size_t)rr * 128 + (col - 128)] =
              (ushort)cvt1(acc[nt][j] + bias[nt]);
      }
    }
    if (w == 3) {                          // fused attention columns
      floatx4 acca = {0, 0, 0, 0};
#pragma unroll
      for (int kt = 0; kt < 4; ++kt)
        acca = __builtin_amdgcn_mfma_f32_16x16x32_bf16(af[kt], bfa[kt],
                                                       acca, 0, 0, 0);
      if (colq < 4) {
        float* dstp = (colq < 2) ? attn_s : attn_d;
        const int c2 = colq & 1;
#pragma unroll
        for (int j = 0; j < 4; ++j) {
          const int rr = row0 + kgrp * 4 + j;
          dstp[2 * rr + c2] = acca[j];
        }
      }
    }
  }
}

// ---------------------------------------------------------------------------
// Bucket append (dst>>11, 49 buckets of 2048 nodes). Record (u64):
// [src:17 | dloc:11 | w0bf16 | w1bf16]. Two-pass with register-cached dst.
// ---------------------------------------------------------------------------
__global__ __launch_bounds__(1024) void bucket_kernel(
    const int* __restrict__ src, const int* __restrict__ dst,
    const float2* __restrict__ attn_s, const float2* __restrict__ attn_d,
    int* __restrict__ bucket_next, unsigned long long* __restrict__ tmp)
{
  __shared__ int lofs[NBUCK];
  const int t = threadIdx.x;
  if (t < NBUCK) lofs[t] = 0;
  __syncthreads();

  const int e0 = blockIdx.x * CHUNK1;
  const int e1 = min(e0 + CHUNK1, NE);

  int dreg[4];
#pragma unroll
  for (int k = 0; k < 4; ++k) {
    const int e = e0 + k * 1024 + t;
    dreg[k] = (e < e1) ? dst[e] : -1;
    if (e < e1) atomicAdd(&lofs[dreg[k] >> 11], 1);
  }
  __syncthreads();

  if (t < NBUCK) {
    const int c = lofs[t];
    const int base = atomicAdd(&bucket_next[t], c);
    lofs[t] = t * BCAP + base;
  }
  __syncthreads();

#pragma unroll
  for (int k = 0; k < 4; ++k) {
    const int e = e0 + k * 1024 + t;
    if (e < e1) {
      const int d = dreg[k];
      const int s = src[e];
      const float2 as = attn_s[s];
      const float2 ad = attn_d[d];
      float l0 = as.x + ad.x;
      float l1 = as.y + ad.y;
      l0 = (l0 > 0.0f) ? l0 : NEG * l0;
      l1 = (l1 > 0.0f) ? l1 : NEG * l1;
      const uint32_t wp = cvt1(__expf(l0)) | (cvt1(__expf(l1)) << 16);
      const int pos = atomicAdd(&lofs[d >> 11], 1);
      tmp[pos] = ((unsigned long long)(unsigned)s << 43)
               | ((unsigned long long)(unsigned)(d & 2047) << 32)
               | (unsigned long long)wp;
    }
  }
}

// ---------------------------------------------------------------------------
// Fused rs-build + CSR scatter: one block per 2048-node bucket (R10-proven).
// ---------------------------------------------------------------------------
__global__ __launch_bounds__(1024) void rs_csr_kernel(
    const unsigned long long* __restrict__ tmp,
    const int* __restrict__ bucket_next,
    int* __restrict__ rs, uint2* __restrict__ edges)
{
  __shared__ int hist[2048];
  __shared__ int ps[1024];
  __shared__ int bstart_s;
  const int b = blockIdx.x;
  const int t = threadIdx.x;
  hist[t] = 0;
  hist[t + 1024] = 0;
  if (t == 0) {
    int ssum = 0;
    for (int k = 0; k < b; ++k) ssum += bucket_next[k];
    bstart_s = ssum;
  }
  __syncthreads();

  const int ncnt = bucket_next[b];
  const unsigned long long* base = tmp + (size_t)b * BCAP;
  for (int i = t; i < ncnt; i += 1024)
    atomicAdd(&hist[(int)((base[i] >> 32) & 2047)], 1);
  __syncthreads();

  const int h0 = hist[2 * t];
  const int h1 = hist[2 * t + 1];
  const int pv = h0 + h1;
  ps[t] = pv;
  __syncthreads();
  int x = pv;
  for (int o = 1; o < 1024; o <<= 1) {
    const int y = (t >= o) ? ps[t - o] : 0;
    __syncthreads();
    x += y;
    ps[t] = x;
    __syncthreads();
  }
  const int e0 = bstart_s + x - pv;          // exclusive prefix at node 2t
  hist[2 * t]     = e0;                      // becomes running write cursor
  hist[2 * t + 1] = e0 + h0;
  const int n0 = b * 2048 + 2 * t;
  if (n0 < NN)     rs[n0] = e0;
  if (n0 + 1 < NN) rs[n0 + 1] = e0 + h0;
  if (b == NBUCK - 1 && t == 0) rs[NN] = NE;
  __syncthreads();

  for (int i = t; i < ncnt; i += 1024) {
    const unsigned long long r = base[i];
    const int s = (int)(r >> 43);
    const int dloc = (int)((r >> 32) & 2047);
    const int pos = atomicAdd(&hist[dloc], 1);
    edges[pos] = make_uint2((unsigned)s * 256u, (uint32_t)r);
  }
}

// ---------------------------------------------------------------------------
// Aggregation: one wave per destination node (proven 77 us structure);
// 8 B records (bf16 weights); 3-stage, 8-edge-wide pipeline; writes
// out = agg/denom + dst_fc for every node (no RMW of out).
// ---------------------------------------------------------------------------
__global__ __launch_bounds__(256) void aggregate_kernel(
    const int* __restrict__ rs, const uint2* __restrict__ edges,
    const ushort* __restrict__ src_fc, const ushort* __restrict__ dst_fc,
    float* __restrict__ out)
{
  int wid = (int)((blockIdx.x * (size_t)blockDim.x + threadIdx.x) >> 6);
  if (wid >= NN) return;
  wid = __builtin_amdgcn_readfirstlane(wid);
  const int lane = threadIdx.x & 63;
  const unsigned lane4 = lane * 4;          // byte offset within bf16 row
  const int start = rs[wid];
  const int end = rs[wid + 1];
  const int deg = end - start;

  // own dst row (residual branch), issued early
  const uint32_t dv =
      *(const uint32_t*)((const char*)dst_fc + ((unsigned)wid * 256u + lane4));
  const float dx = __uint_as_float(dv << 16);
  const float dy = __uint_as_float(dv & 0xffff0000u);
  float2* po = (float2*)(out + (size_t)wid * 128 + 2 * lane);

  if (deg == 0) { *po = make_float2(dx, dy); return; }

  const bool h0 = (lane < 32);
  const char* fcb = (const char*)src_fc;
  const int nb = (deg + 7) >> 3;

  struct Batch { uint2 e[8]; };
  struct Rows  { uint32_t r[8]; };

  auto loadE = [&](int b, Batch& B) {
    const int base = start + b * 8;
#pragma unroll
    for (int j = 0; j < 8; ++j) {
      const int idx = (base + j < end) ? base + j : start;
      B.e[j] = edges[idx];                   // uniform -> scalar loads
    }
  };
  auto loadR = [&](const Batch& B, Rows& R) {
#pragma unroll
    for (int j = 0; j < 8; ++j)
      R.r[j] = *(const uint32_t*)(fcb + (B.e[j].x + lane4));
  };

  float acc0 = 0.0f, acc1 = 0.0f, dh = 0.0f;
  auto compute = [&](int b, const Batch& B, const Rows& R) {
    const int rem = deg - b * 8;
#pragma unroll
    for (int j = 0; j < 8; ++j) {
      const uint32_t wp = (j < rem) ? B.e[j].y : 0u;   // scalar select
      const float w0 = __uint_as_float(wp << 16);
      const float w1 = __uint_as_float(wp & 0xffff0000u);
      const float wh = h0 ? w0 : w1;
      dh += wh;
      acc0 = fmaf(__uint_as_float(R.r[j] << 16), wh, acc0);
      acc1 = fmaf(__uint_as_float(R.r[j] & 0xffff0000u), wh, acc1);
    }
  };

  Batch bA, bB;
  Rows rA;
  loadE(0, bA);
  loadR(bA, rA);
  if (nb > 1) loadE(1, bB); else bB = bA;

  for (int b = 0; b < nb; ++b) {
    Rows rB = rA;
    if (b + 1 < nb) loadR(bB, rB);
    Batch bC = bB;
    if (b + 2 < nb) loadE(b + 2, bC);
    compute(b, bA, rA);
    bA = bB; rA = rB; bB = bC;
  }

  const float inv = 1.0f / dh;
  float2 o;
  o.x = fmaf(acc0, inv, dx);
  o.y = fmaf(acc1, inv, dy);
  *po = o;
}

// ---------------------------------------------------------------------------
extern "C" void kernel_launch(void* const* d_in, const int* in_sizes, int n_in,
                              void* d_out, int out_size, void* d_ws, size_t ws_size,
                              hipStream_t stream)
{
  const float* feat    = (const float*)d_in[0];
  const int*   src_idx = (const int*)d_in[1];
  const int*   dst_idx = (const int*)d_in[2];
  const float* Wsrc    = (const float*)d_in[3];
  const float* Wdst    = (const float*)d_in[4];
  const float* bdst    = (const float*)d_in[5];
  const float* asrc    = (const float*)d_in[6];
  const float* adst    = (const float*)d_in[7];
  float* out = (float*)d_out;

  char* ws = (char*)d_ws;
  size_t off = 0;
  auto alloc = [&](size_t bytes) -> void* {
    void* p = ws + off;
    off = (off + bytes + 255) & ~(size_t)255;
    return p;
  };
  ushort* src_fc  = (ushort*)alloc((size_t)NN * 128 * sizeof(ushort));   // 25.6 MB
  ushort* dst_fc  = (ushort*)alloc((size_t)NN * 128 * sizeof(ushort));   // 25.6 MB
  float*  attn_s  = (float*)alloc((size_t)NN * 2 * sizeof(float));
  float*  attn_d  = (float*)alloc((size_t)NN * 2 * sizeof(float));
  int*    rs      = (int*)alloc((size_t)(NN + 1) * sizeof(int));
  uint2*  edges   = (uint2*)alloc((size_t)NE * sizeof(uint2));           // 12.8 MB
  unsigned long long* tmp =
      (unsigned long long*)alloc((size_t)NBUCK * BCAP * sizeof(unsigned long long)); // 14.5 MB
  int*    bnext   = (int*)alloc((size_t)NBUCK * sizeof(int));
  ushort* wb      = (ushort*)alloc((size_t)272 * 128 * sizeof(ushort));

  hipMemsetAsync(bnext, 0, (size_t)NBUCK * sizeof(int), stream);

  cvt_w_kernel<<<17, 256, 0, stream>>>(Wsrc, Wdst, asrc, adst, wb);
  gemm_kernel<<<1563, 256, 0, stream>>>(feat, wb, bdst, src_fc, dst_fc,
                                        attn_s, attn_d);
  bucket_kernel<<<NBLK1, 1024, 0, stream>>>(
      src_idx, dst_idx, (const float2*)attn_s, (const float2*)attn_d,
      bnext, tmp);
  rs_csr_kernel<<<NBUCK, 1024, 0, stream>>>(tmp, bnext, rs, edges);
  aggregate_kernel<<<(NN * 64) / 256, 256, 0, stream>>>(rs, edges, src_fc,
                                                        dst_fc, out);
}

// Round 14
// 180.632 us; speedup vs baseline: 1.1335x; 1.0124x over previous
//
#include <hip/hip_runtime.h>
#include <cstdint>
#include <cstddef>

static constexpr int NN = 100000;
static constexpr int NE = 1600000;
static constexpr float NEG = 0.2f;
static constexpr int NBUCK = 49;                 // dst >> 11 (2048 nodes/bucket)
static constexpr int BCAP  = 36864;              // mean 32768 + ~22 sigma slack
static constexpr int NBLK1 = 512;
static constexpr int CHUNK1 = (NE + NBLK1 - 1) / NBLK1;  // 3125 (<= 4*1024)

typedef __attribute__((ext_vector_type(8))) short short8v;   // 8 bf16 (4 VGPRs)
typedef __attribute__((ext_vector_type(4))) float floatx4;   // 4 f32 acc

// ---------------------------------------------------------------------------
__device__ inline short8v cvt8(const float4 a, const float4 b)
{
  const float v[8] = {a.x, a.y, a.z, a.w, b.x, b.y, b.z, b.w};
  uint32_t q[8];
#pragma unroll
  for (int j = 0; j < 8; ++j) {
    uint32_t u = __float_as_uint(v[j]);
    u += 0x7fff + ((u >> 16) & 1);   // round-to-nearest-even
    q[j] = u >> 16;
  }
  union { uint32_t u[4]; short8v s; } r;
  r.u[0] = q[0] | (q[1] << 16);
  r.u[1] = q[2] | (q[3] << 16);
  r.u[2] = q[4] | (q[5] << 16);
  r.u[3] = q[6] | (q[7] << 16);
  return r.s;
}

__device__ inline uint32_t cvt1(float x)
{
  uint32_t u = __float_as_uint(x);
  u += 0x7fff + ((u >> 16) & 1);
  return u >> 16;
}

// ---------------------------------------------------------------------------
// Build wb[272][128] bf16: rows 0-127 Wsrc, 128-255 Wdst, 256-257 a_src,
// 258-259 a_dst, 260-271 zero pad (attn = 4 extra GEMM columns).
// ---------------------------------------------------------------------------
__global__ __launch_bounds__(256) void cvt_w_kernel(
    const float* __restrict__ Wsrc, const float* __restrict__ Wdst,
    const float* __restrict__ asrc, const float* __restrict__ adst,
    ushort* __restrict__ wb)
{
  const int i = (blockIdx.x * 256 + threadIdx.x) * 8;
  if (i >= 34816) return;
  const float* src;
  if (i < 16384)      src = Wsrc + i;
  else if (i < 32768) src = Wdst + (i - 16384);
  else if (i < 33024) src = asrc + (i - 32768);
  else if (i < 33280) src = adst + (i - 33024);
  else { *(short8v*)(wb + i) = short8v{0,0,0,0,0,0,0,0}; return; }
  float4 a = *(const float4*)(src);
  float4 b = *(const float4*)(src + 4);
  *(short8v*)(wb + i) = cvt8(a, b);
}

// ---------------------------------------------------------------------------
// MFMA projection GEMM (R10-proven): A staged once per block through
// swizzled LDS; B from pre-converted bf16 wb; wave 3 computes the 4 fused
// attn-logit columns. Outputs src_fc bf16, dst_fc bf16 (+bias), attn f32.
// ---------------------------------------------------------------------------
__global__ __launch_bounds__(256) void gemm_kernel(
    const float* __restrict__ feat, const ushort* __restrict__ wb,
    const float* __restrict__ bdst,
    ushort* __restrict__ src_fc, ushort* __restrict__ dst_fc,
    float* __restrict__ attn_s, float* __restrict__ attn_d)
{
  __shared__ __align__(16) ushort atile[2048];   // 16 x 128 bf16, swizzled

  const int t    = threadIdx.x;
  const int lane = t & 63;
  const int w    = t >> 6;                 // wave 0..3
  const int c0   = w * 64;
  const int colq = lane & 15;
  const int kgrp = lane >> 4;

  short8v bf[4][4];
#pragma unroll
  for (int nt = 0; nt < 4; ++nt)
#pragma unroll
    for (int kt = 0; kt < 4; ++kt)
      bf[nt][kt] = *(const short8v*)(wb + (size_t)(c0 + nt * 16 + colq) * 128
                                        + kt * 32 + kgrp * 8);
  short8v bfa[4];
  if (w == 3) {
#pragma unroll
    for (int kt = 0; kt < 4; ++kt)
      bfa[kt] = *(const short8v*)(wb + (size_t)(256 + colq) * 128
                                     + kt * 32 + kgrp * 8);
  }

  float bias[4];
#pragma unroll
  for (int nt = 0; nt < 4; ++nt) {
    const int col = c0 + nt * 16 + colq;
    bias[nt] = (col >= 128) ? bdst[col - 128] : 0.0f;
  }
  const bool is_dst = (c0 >= 128);

  const int sr = t >> 4;                   // staging row 0..15
  const int sc = t & 15;                   // staging col-group (8 floats)
  const unsigned sw_off = (unsigned)((sr * 256 + sc * 16) ^ ((sr & 7) << 4));
  unsigned rd_off[4];
#pragma unroll
  for (int kt = 0; kt < 4; ++kt)
    rd_off[kt] = (unsigned)((colq * 256 + kt * 64 + kgrp * 16) ^ ((colq & 7) << 4));

  for (int mt = blockIdx.x; mt < NN / 16; mt += gridDim.x) {
    const int row0 = mt * 16;
    {
      const float* ap = feat + (size_t)(row0 + sr) * 128 + sc * 8;
      float4 a = *(const float4*)ap;
      float4 b = *(const float4*)(ap + 4);
      *(short8v*)((char*)atile + sw_off) = cvt8(a, b);
    }
    __syncthreads();
    short8v af[4];
#pragma unroll
    for (int kt = 0; kt < 4; ++kt)
      af[kt] = *(const short8v*)((const char*)atile + rd_off[kt]);
    __syncthreads();   // reads drained before next iter's writes

    floatx4 acc[4] = {{0,0,0,0},{0,0,0,0},{0,0,0,0},{0,0,0,0}};
#pragma unroll
    for (int kt = 0; kt < 4; ++kt)
#pragma unroll
      for (int nt = 0; nt < 4; ++nt)
        acc[nt] = __builtin_amdgcn_mfma_f32_16x16x32_bf16(af[kt], bf[nt][kt],
                                                          acc[nt], 0, 0, 0);
    // C/D: col = lane&15, row = (lane>>4)*4 + reg
#pragma unroll
    for (int nt = 0; nt < 4; ++nt) {
      const int col = c0 + nt * 16 + colq;
#pragma unroll
      for (int j = 0; j < 4; ++j) {
        const int rr = row0 + kgrp * 4 + j;
        if (!is_dst)
          src_fc[(size_t)rr * 128 + col] = (ushort)cvt1(acc[nt][j]);
        else
          dst_fc[(size_t)rr * 128 + (col - 128)] =
              (ushort)cvt1(acc[nt][j] + bias[nt]);
      }
    }
    if (w == 3) {                          // fused attention columns
      floatx4 acca = {0, 0, 0, 0};
#pragma unroll
      for (int kt = 0; kt < 4; ++kt)
        acca = __builtin_amdgcn_mfma_f32_16x16x32_bf16(af[kt], bfa[kt],
                                                       acca, 0, 0, 0);
      if (colq < 4) {
        float* dstp = (colq < 2) ? attn_s : attn_d;
        const int c2 = colq & 1;
#pragma unroll
        for (int j = 0; j < 4; ++j) {
          const int rr = row0 + kgrp * 4 + j;
          dstp[2 * rr + c2] = acca[j];
        }
      }
    }
  }
}

// ---------------------------------------------------------------------------
// Bucket append (dst>>11, 49 buckets of 2048 nodes). Record (u64):
// [src:17 | dloc:11 | w0bf16 | w1bf16]. Two-pass with register-cached dst.
// ---------------------------------------------------------------------------
__global__ __launch_bounds__(1024) void bucket_kernel(
    const int* __restrict__ src, const int* __restrict__ dst,
    const float2* __restrict__ attn_s, const float2* __restrict__ attn_d,
    int* __restrict__ bucket_next, unsigned long long* __restrict__ tmp)
{
  __shared__ int lofs[NBUCK];
  const int t = threadIdx.x;
  if (t < NBUCK) lofs[t] = 0;
  __syncthreads();

  const int e0 = blockIdx.x * CHUNK1;
  const int e1 = min(e0 + CHUNK1, NE);

  int dreg[4];
#pragma unroll
  for (int k = 0; k < 4; ++k) {
    const int e = e0 + k * 1024 + t;
    dreg[k] = (e < e1) ? dst[e] : -1;
    if (e < e1) atomicAdd(&lofs[dreg[k] >> 11], 1);
  }
  __syncthreads();

  if (t < NBUCK) {
    const int c = lofs[t];
    const int base = atomicAdd(&bucket_next[t], c);
    lofs[t] = t * BCAP + base;
  }
  __syncthreads();

#pragma unroll
  for (int k = 0; k < 4; ++k) {
    const int e = e0 + k * 1024 + t;
    if (e < e1) {
      const int d = dreg[k];
      const int s = src[e];
      const float2 as = attn_s[s];
      const float2 ad = attn_d[d];
      float l0 = as.x + ad.x;
      float l1 = as.y + ad.y;
      l0 = (l0 > 0.0f) ? l0 : NEG * l0;
      l1 = (l1 > 0.0f) ? l1 : NEG * l1;
      const uint32_t wp = cvt1(__expf(l0)) | (cvt1(__expf(l1)) << 16);
      const int pos = atomicAdd(&lofs[d >> 11], 1);
      tmp[pos] = ((unsigned long long)(unsigned)s << 43)
               | ((unsigned long long)(unsigned)(d & 2047) << 32)
               | (unsigned long long)wp;
    }
  }
}

// ---------------------------------------------------------------------------
// Fused rs-build + CSR scatter: one block per 2048-node bucket (R10-proven).
// ---------------------------------------------------------------------------
__global__ __launch_bounds__(1024) void rs_csr_kernel(
    const unsigned long long* __restrict__ tmp,
    const int* __restrict__ bucket_next,
    int* __restrict__ rs, uint2* __restrict__ edges)
{
  __shared__ int hist[2048];
  __shared__ int ps[1024];
  __shared__ int bstart_s;
  const int b = blockIdx.x;
  const int t = threadIdx.x;
  hist[t] = 0;
  hist[t + 1024] = 0;
  if (t == 0) {
    int ssum = 0;
    for (int k = 0; k < b; ++k) ssum += bucket_next[k];
    bstart_s = ssum;
  }
  __syncthreads();

  const int ncnt = bucket_next[b];
  const unsigned long long* base = tmp + (size_t)b * BCAP;
  for (int i = t; i < ncnt; i += 1024)
    atomicAdd(&hist[(int)((base[i] >> 32) & 2047)], 1);
  __syncthreads();

  const int h0 = hist[2 * t];
  const int h1 = hist[2 * t + 1];
  const int pv = h0 + h1;
  ps[t] = pv;
  __syncthreads();
  int x = pv;
  for (int o = 1; o < 1024; o <<= 1) {
    const int y = (t >= o) ? ps[t - o] : 0;
    __syncthreads();
    x += y;
    ps[t] = x;
    __syncthreads();
  }
  const int e0 = bstart_s + x - pv;          // exclusive prefix at node 2t
  hist[2 * t]     = e0;                      // becomes running write cursor
  hist[2 * t + 1] = e0 + h0;
  const int n0 = b * 2048 + 2 * t;
  if (n0 < NN)     rs[n0] = e0;
  if (n0 + 1 < NN) rs[n0 + 1] = e0 + h0;
  if (b == NBUCK - 1 && t == 0) rs[NN] = NE;
  __syncthreads();

  for (int i = t; i < ncnt; i += 1024) {
    const unsigned long long r = base[i];
    const int s = (int)(r >> 43);
    const int dloc = (int)((r >> 32) & 2047);
    const int pos = atomicAdd(&hist[dloc], 1);
    edges[pos] = make_uint2((unsigned)s * 256u, (uint32_t)r);
  }
}

// ---------------------------------------------------------------------------
// Aggregation: TWO nodes per wave with interleaved pipelines — node B's
// gathers issue while node A computes, doubling per-wave memory-level
// parallelism (the 77us plateau was per-node latency-chain-bound).
// ---------------------------------------------------------------------------
__global__ __launch_bounds__(256) void aggregate_kernel(
    const int* __restrict__ rs, const uint2* __restrict__ edges,
    const ushort* __restrict__ src_fc, const ushort* __restrict__ dst_fc,
    float* __restrict__ out)
{
  int wv = (int)((blockIdx.x * (size_t)blockDim.x + threadIdx.x) >> 6);
  if (wv >= NN / 2) return;
  wv = __builtin_amdgcn_readfirstlane(wv);
  const int nA = wv * 2;
  const int nB = nA + 1;
  const int lane = threadIdx.x & 63;
  const unsigned lane4 = lane * 4;
  const bool h0 = (lane < 32);
  const char* fcb = (const char*)src_fc;

  const int sA = rs[nA];
  const int eA = rs[nA + 1];
  const int eB = rs[nA + 2];
  const int sB = eA;
  const int degA = eA - sA;
  const int degB = eB - sB;

  // both dst rows issued immediately (independent loads)
  const uint32_t dvA =
      *(const uint32_t*)((const char*)dst_fc + ((unsigned)nA * 256u + lane4));
  const uint32_t dvB =
      *(const uint32_t*)((const char*)dst_fc + ((unsigned)nB * 256u + lane4));

  const int nbA = (degA + 7) >> 3;
  const int nbB = (degB + 7) >> 3;
  const int nb = (nbA > nbB) ? nbA : nbB;

  float2* poA = (float2*)(out + (size_t)nA * 128 + 2 * lane);
  float2* poB = (float2*)(out + (size_t)nB * 128 + 2 * lane);
  const float dAx = __uint_as_float(dvA << 16);
  const float dAy = __uint_as_float(dvA & 0xffff0000u);
  const float dBx = __uint_as_float(dvB << 16);
  const float dBy = __uint_as_float(dvB & 0xffff0000u);

  if (nb == 0) {
    *poA = make_float2(dAx, dAy);
    *poB = make_float2(dBx, dBy);
    return;
  }

  struct Batch { uint2 e[8]; };
  struct Rows  { uint32_t r[8]; };

  auto loadE = [&](int st, int en, int b, Batch& Bt) {
#pragma unroll
    for (int j = 0; j < 8; ++j) {
      const int ix = st + b * 8 + j;
      const int idx = (ix < en) ? ix : 0;    // always-safe clamp
      Bt.e[j] = edges[idx];                  // uniform -> scalar loads
    }
  };
  auto loadR = [&](const Batch& Bt, Rows& R) {
#pragma unroll
    for (int j = 0; j < 8; ++j)
      R.r[j] = *(const uint32_t*)(fcb + (Bt.e[j].x + lane4));
  };

  float aA0 = 0.0f, aA1 = 0.0f, dhA = 0.0f;
  float aB0 = 0.0f, aB1 = 0.0f, dhB = 0.0f;
  auto computeN = [&](int deg, int b, const Batch& Bt, const Rows& R,
                      float& a0, float& a1, float& dh) {
    const int rem = deg - b * 8;
#pragma unroll
    for (int j = 0; j < 8; ++j) {
      const uint32_t wp = (j < rem) ? Bt.e[j].y : 0u;   // scalar select
      const float w0 = __uint_as_float(wp << 16);
      const float w1 = __uint_as_float(wp & 0xffff0000u);
      const float wh = h0 ? w0 : w1;
      dh += wh;
      a0 = fmaf(__uint_as_float(R.r[j] << 16), wh, a0);
      a1 = fmaf(__uint_as_float(R.r[j] & 0xffff0000u), wh, a1);
    }
  };

  Batch bAc, bAn, bBc, bBn;    // current / next per node
  Rows  rAc, rAn, rBc, rBn;

  loadE(sA, eA, 0, bAc);
  loadE(sB, eB, 0, bBc);
  loadR(bAc, rAc);
  loadR(bBc, rBc);
  if (nbA > 1) loadE(sA, eA, 1, bAn);
  if (nbB > 1) loadE(sB, eB, 1, bBn);

  for (int b = 0; b < nb; ++b) {
    if (b + 1 < nbA) loadR(bAn, rAn);
    if (b + 1 < nbB) loadR(bBn, rBn);
    if (b < nbA) computeN(degA, b, bAc, rAc, aA0, aA1, dhA);
    if (b < nbB) computeN(degB, b, bBc, rBc, aB0, aB1, dhB);
    if (b + 1 < nbA) {
      bAc = bAn; rAc = rAn;
      if (b + 2 < nbA) loadE(sA, eA, b + 2, bAn);
    }
    if (b + 1 < nbB) {
      bBc = bBn; rBc = rBn;
      if (b + 2 < nbB) loadE(sB, eB, b + 2, bBn);
    }
  }

  float2 oA, oB;
  if (degA > 0) {
    const float inv = 1.0f / dhA;
    oA.x = fmaf(aA0, inv, dAx);
    oA.y = fmaf(aA1, inv, dAy);
  } else {
    oA = make_float2(dAx, dAy);
  }
  if (degB > 0) {
    const float inv = 1.0f / dhB;
    oB.x = fmaf(aB0, inv, dBx);
    oB.y = fmaf(aB1, inv, dBy);
  } else {
    oB = make_float2(dBx, dBy);
  }
  *poA = oA;
  *poB = oB;
}

// ---------------------------------------------------------------------------
extern "C" void kernel_launch(void* const* d_in, const int* in_sizes, int n_in,
                              void* d_out, int out_size, void* d_ws, size_t ws_size,
                              hipStream_t stream)
{
  const float* feat    = (const float*)d_in[0];
  const int*   src_idx = (const int*)d_in[1];
  const int*   dst_idx = (const int*)d_in[2];
  const float* Wsrc    = (const float*)d_in[3];
  const float* Wdst    = (const float*)d_in[4];
  const float* bdst    = (const float*)d_in[5];
  const float* asrc    = (const float*)d_in[6];
  const float* adst    = (const float*)d_in[7];
  float* out = (float*)d_out;

  char* ws = (char*)d_ws;
  size_t off = 0;
  auto alloc = [&](size_t bytes) -> void* {
    void* p = ws + off;
    off = (off + bytes + 255) & ~(size_t)255;
    return p;
  };
  ushort* src_fc  = (ushort*)alloc((size_t)NN * 128 * sizeof(ushort));   // 25.6 MB
  ushort* dst_fc  = (ushort*)alloc((size_t)NN * 128 * sizeof(ushort));   // 25.6 MB
  float*  attn_s  = (float*)alloc((size_t)NN * 2 * sizeof(float));
  float*  attn_d  = (float*)alloc((size_t)NN * 2 * sizeof(float));
  int*    rs      = (int*)alloc((size_t)(NN + 1) * sizeof(int));
  uint2*  edges   = (uint2*)alloc((size_t)NE * sizeof(uint2));           // 12.8 MB
  unsigned long long* tmp =
      (unsigned long long*)alloc((size_t)NBUCK * BCAP * sizeof(unsigned long long)); // 14.5 MB
  int*    bnext   = (int*)alloc((size_t)NBUCK * sizeof(int));
  ushort* wb      = (ushort*)alloc((size_t)272 * 128 * sizeof(ushort));

  hipMemsetAsync(bnext, 0, (size_t)NBUCK * sizeof(int), stream);

  cvt_w_kernel<<<17, 256, 0, stream>>>(Wsrc, Wdst, asrc, adst, wb);
  gemm_kernel<<<1563, 256, 0, stream>>>(feat, wb, bdst, src_fc, dst_fc,
                                        attn_s, attn_d);
  bucket_kernel<<<NBLK1, 1024, 0, stream>>>(
      src_idx, dst_idx, (const float2*)attn_s, (const float2*)attn_d,
      bnext, tmp);
  rs_csr_kernel<<<NBUCK, 1024, 0, stream>>>(tmp, bnext, rs, edges);
  aggregate_kernel<<<(NN / 2 * 64) / 256, 256, 0, stream>>>(rs, edges, src_fc,
                                                            dst_fc, out);
}